// Round 9
// baseline (416.076 us; speedup 1.0000x reference)
//
#include <hip/hip_runtime.h>
#include <hip/hip_bf16.h>

#define BB 4
#define NN 2048
#define NROWS (BB*NN)   // 8192

typedef unsigned short u16;
typedef __bf16 bf16x8 __attribute__((ext_vector_type(8)));
typedef u16    u16x8  __attribute__((ext_vector_type(8)));
typedef float  fx4    __attribute__((ext_vector_type(4)));

__device__ __forceinline__ float bf2f(u16 u){
  union { float f; unsigned int i; } x; x.i = ((unsigned int)u) << 16; return x.f;
}
__device__ __forceinline__ u16 f2bf(float f){
  union { float f; unsigned int i; } x; x.f = f;
  unsigned int i = x.i;
  i += 0x7fffu + ((i >> 16) & 1u);
  return (u16)(i >> 16);
}
__device__ __forceinline__ float geluf(float x){
  return 0.5f * x * (1.0f + erff(x * 0.70710678118654752f));
}

// flags[0]=1 if float inputs fp32 (else bf16); flags[1]=1 if mask byte-packed
__global__ __launch_bounds__(256) void sniff_k(const u16* tokens, const unsigned int* mask, int* flags){
  __shared__ int s_f32, s_byte;
  if (threadIdx.x == 0) { s_f32 = 0; s_byte = 0; }
  __syncthreads();
  for (int i = threadIdx.x; i < 4096; i += 256) {
    float v = bf2f(tokens[i]);
    if (!(fabsf(v) < 1e10f)) atomicOr(&s_f32, 1);
  }
  for (int i = threadIdx.x; i < 2048; i += 256) {
    if (mask[i] > 1u) atomicOr(&s_byte, 1);
  }
  __syncthreads();
  if (threadIdx.x == 0) { flags[0] = s_f32; flags[1] = s_byte; }
}

// rope + m32 + params + zero(ctx,kS) + tokbf in one grid-stride launch
__global__ __launch_bounds__(256) void misc_k(const void* mask, const void* tokens,
                                              const void* p0, const void* p1, const void* p2,
                                              const void* p3, const void* p4, const void* p5,
                                              const void* p6, const void* p7,
                                              const int* flags, float* rope, int* m32,
                                              float* params, float* ctx, float* kS, u16* tokbf){
  const void* srcs[8] = {p0,p1,p2,p3,p4,p5,p6,p7};
  int f32 = flags[0], mbyte = flags[1];
  const int T = 131072 + 8192 + 4096 + 131072 + 2048 + 4194304;
  for (int i = blockIdx.x*256 + threadIdx.x; i < T; i += gridDim.x*256) {
    if (i < 131072) {
      int p = i >> 6, j = i & 63;
      int jj = (j < 32) ? j : j - 32;
      float invf = exp2f(-(float)jj * (13.287712379549449f/32.0f));  // 10000^(-jj/32)
      float prod = (float)p * invf;
      rope[i] = (j < 32) ? sinf(prod) : cosf(prod);
    } else if (i < 139264) {
      int k = i - 131072;
      int v = mbyte ? (int)((const unsigned char*)mask)[k] : ((const int*)mask)[k];
      m32[k] = v ? 1 : 0;
    } else if (i < 143360) {
      int k = i - 139264;
      int pid = k >> 9, j = k & 511;
      const void* s = srcs[pid];
      params[k] = f32 ? ((const float*)s)[j] : bf2f(((const u16*)s)[j]);
    } else if (i < 274432) {
      ctx[i - 143360] = 0.0f;
    } else if (i < 276480) {
      kS[i - 274432] = 0.0f;
    } else {
      int k = i - 276480;
      tokbf[k] = f32 ? f2bf(((const float*)tokens)[k]) : ((const u16*)tokens)[k];
    }
  }
}

// merged weight prep: blocks [0,1024): conv weights w[o][c][kk] -> W2[kk][o][c];
// blocks [1024,1600): LDS tile transpose [K][N]->[N][K] for the three dense weights
__global__ __launch_bounds__(256) void prep2_k(const void* w_qkv, const void* w_out, const void* ff_w,
                                               const void* w_narrow, const void* w_wide,
                                               const int* flags,
                                               u16* wqkvt, u16* woutt, u16* ffwt,
                                               u16* wtN2, u16* wtW2){
  int bid = blockIdx.x;
  int f = flags[0];
  int tid = threadIdx.x;
  if (bid < 1024) {
    int tensor = bid >> 9, o = bid & 511;
    const void* src = tensor ? w_wide : w_narrow;
    u16* dst = tensor ? wtW2 : wtN2;
    __shared__ u16 Ls[4608];
    for (int i = tid; i < 4608; i += 256) {
      Ls[i] = f ? f2bf(((const float*)src)[(size_t)o*4608 + i]) : ((const u16*)src)[(size_t)o*4608 + i];
    }
    __syncthreads();
    #pragma unroll
    for (int kk = 0; kk < 9; kk++) {
      #pragma unroll
      for (int u = 0; u < 2; u++) {
        int c = tid + u*256;
        dst[(size_t)kk*262144 + o*512 + c] = Ls[c*9 + kk];
      }
    }
  } else {
    int id = bid - 1024;
    int z = id / 192;
    int rem = id - z*192;
    int x = rem % 24, y = rem / 24;
    int Nn = (z == 0) ? 1536 : 512;
    if (x * 64 >= Nn) return;
    const void* src = (z == 0) ? w_qkv : (z == 1) ? w_out : ff_w;
    u16* dst = (z == 0) ? wqkvt : (z == 1) ? woutt : ffwt;
    __shared__ u16 Ts[64][72];
    int n0 = x * 64, k0 = y * 64;
    int r = tid >> 2, cq = (tid & 3) * 16;
    #pragma unroll
    for (int u = 0; u < 2; u++) {
      int c = cq + u*8;
      int sidx = (k0 + r)*Nn + n0 + c;
      u16x8 v;
      if (f) {
        #pragma unroll
        for (int j = 0; j < 8; j++) v[j] = f2bf(((const float*)src)[sidx + j]);
      } else {
        v = *(const u16x8*)&((const u16*)src)[sidx];
      }
      *(u16x8*)&Ts[r][c] = v;
    }
    __syncthreads();
    #pragma unroll
    for (int u = 0; u < 2; u++) {
      int c = cq + u*8;
      u16x8 v;
      #pragma unroll
      for (int j = 0; j < 8; j++) v[j] = Ts[c + j][r];
      *(u16x8*)&dst[(size_t)(n0 + r)*512 + k0 + c] = v;
    }
  }
}

// ---- qkv GEMM (128x128 tile) with fused q-softmax / k-exp / v-mask epilogue ----
// blockIdx.x: 0..3 -> q cols, 4..7 -> k cols, 8..11 -> v cols. M=0 softmax trick (exact).
__global__ __launch_bounds__(256) void mgemm_qkv_k(const u16* A, const u16* Bt, const float* rope,
                                                   const int* mask, u16* qb, u16* keb, u16* vb){
  __shared__ u16 As[128][40];
  __shared__ u16 Bs[128][40];
  __shared__ int smask[128];
  int tid = threadIdx.x;
  int lane = tid & 63;
  int wave = tid >> 6;
  int wm = (wave >> 1) * 64, wn = (wave & 1) * 64;
  int quad = lane >> 4, l16 = lane & 15;
  int m0 = blockIdx.y * 128, n0 = blockIdx.x * 128;
  fx4 acc[4][4] = {};
  int ar = tid >> 2;
  int ac = (tid & 3) * 8;
  for (int k0 = 0; k0 < 512; k0 += 32) {
    *(u16x8*)&As[ar][ac]    = *(const u16x8*)&A[(size_t)(m0+ar)*512 + k0 + ac];
    *(u16x8*)&As[ar+64][ac] = *(const u16x8*)&A[(size_t)(m0+ar+64)*512 + k0 + ac];
    *(u16x8*)&Bs[ar][ac]    = *(const u16x8*)&Bt[(size_t)(n0+ar)*512 + k0 + ac];
    *(u16x8*)&Bs[ar+64][ac] = *(const u16x8*)&Bt[(size_t)(n0+ar+64)*512 + k0 + ac];
    __syncthreads();
    bf16x8 af[4], bfv[4];
    #pragma unroll
    for (int i = 0; i < 4; i++)
      af[i] = __builtin_bit_cast(bf16x8, *(const u16x8*)&As[wm + i*16 + l16][quad*8]);
    #pragma unroll
    for (int j = 0; j < 4; j++)
      bfv[j] = __builtin_bit_cast(bf16x8, *(const u16x8*)&Bs[wn + j*16 + l16][quad*8]);
    #pragma unroll
    for (int i = 0; i < 4; i++)
      #pragma unroll
      for (int j = 0; j < 4; j++)
        acc[i][j] = __builtin_amdgcn_mfma_f32_16x16x32_bf16(af[i], bfv[j], acc[i][j], 0, 0, 0);
    __syncthreads();
  }
  int x = blockIdx.x;
  if (x >= 4) {
    if (tid < 128) smask[tid] = mask[m0 + tid];
    __syncthreads();
  }
  if (x < 4) {
    // q: softmax over d (64 cols = 4 regs x 16 lanes), scale 1/8, bf16 out
    #pragma unroll
    for (int i = 0; i < 4; i++)
      #pragma unroll
      for (int r = 0; r < 4; r++) {
        int rl = wm + i*16 + quad*4 + r;
        int row = m0 + rl;
        int nseq = row & (NN-1);
        const float* rp = rope + nseq*64 + l16;
        float e0 = __expf(acc[i][0][r] + rp[0]);
        float e1 = __expf(acc[i][1][r] + rp[16]);
        float e2 = __expf(acc[i][2][r] + rp[32]);
        float e3 = __expf(acc[i][3][r] + rp[48]);
        float s = e0 + e1 + e2 + e3;
        s += __shfl_xor(s, 1); s += __shfl_xor(s, 2);
        s += __shfl_xor(s, 4); s += __shfl_xor(s, 8);
        float sc = 0.125f / s;
        size_t base = (size_t)row*512 + n0 + wn + l16;
        qb[base]      = f2bf(e0*sc);
        qb[base + 16] = f2bf(e1*sc);
        qb[base + 32] = f2bf(e2*sc);
        qb[base + 48] = f2bf(e3*sc);
      }
  } else if (x < 8) {
    // k: ke = mask ? exp(k + rope) : 0 (bf16)
    #pragma unroll
    for (int i = 0; i < 4; i++)
      #pragma unroll
      for (int r = 0; r < 4; r++) {
        int rl = wm + i*16 + quad*4 + r;
        int row = m0 + rl;
        int nseq = row & (NN-1);
        int mk = smask[rl];
        const float* rp = rope + nseq*64 + l16;
        size_t base = (size_t)row*512 + (n0 - 512) + wn + l16;
        #pragma unroll
        for (int j = 0; j < 4; j++) {
          float ke = mk ? __expf(acc[i][j][r] + rp[j*16]) : 0.0f;
          keb[base + j*16] = f2bf(ke);
        }
      }
  } else {
    // v: masked bf16
    #pragma unroll
    for (int i = 0; i < 4; i++)
      #pragma unroll
      for (int r = 0; r < 4; r++) {
        int rl = wm + i*16 + quad*4 + r;
        int row = m0 + rl;
        int mk = smask[rl];
        size_t base = (size_t)row*512 + (n0 - 1024) + wn + l16;
        #pragma unroll
        for (int j = 0; j < 4; j++)
          vb[base + j*16] = mk ? f2bf(acc[i][j][r]) : (u16)0;
      }
  }
}

#define FMA16(a, b, acc) \
  acc[0][0] = fmaf(a.x, b.x, acc[0][0]); acc[0][1] = fmaf(a.x, b.y, acc[0][1]); \
  acc[0][2] = fmaf(a.x, b.z, acc[0][2]); acc[0][3] = fmaf(a.x, b.w, acc[0][3]); \
  acc[1][0] = fmaf(a.y, b.x, acc[1][0]); acc[1][1] = fmaf(a.y, b.y, acc[1][1]); \
  acc[1][2] = fmaf(a.y, b.z, acc[1][2]); acc[1][3] = fmaf(a.y, b.w, acc[1][3]); \
  acc[2][0] = fmaf(a.z, b.x, acc[2][0]); acc[2][1] = fmaf(a.z, b.y, acc[2][1]); \
  acc[2][2] = fmaf(a.z, b.z, acc[2][2]); acc[2][3] = fmaf(a.z, b.w, acc[2][3]); \
  acc[3][0] = fmaf(a.w, b.x, acc[3][0]); acc[3][1] = fmaf(a.w, b.y, acc[3][1]); \
  acc[3][2] = fmaf(a.w, b.z, acc[3][2]); acc[3][3] = fmaf(a.w, b.w, acc[3][3]);

// ctx[bh][d][e] += sum_n ke[n,d]*v[n,e] (bf16 inputs, exp/mask pre-applied); S[bh][d] += sum ke
__global__ __launch_bounds__(256) void ctx_k(const u16* keb, const u16* vb, float* ctx, float* Sg){
  int bh = blockIdx.x, seg = blockIdx.y;
  int b = bh >> 3, h = bh & 7;
  __shared__ float Ks[32][68], Vs[32][68];
  __shared__ float sS[64];
  int tid = threadIdx.x, tx = tid & 15, ty = tid >> 4;
  if (tid < 64) sS[tid] = 0.0f;
  float acc[4][4] = {{0.f,0.f,0.f,0.f},{0.f,0.f,0.f,0.f},{0.f,0.f,0.f,0.f},{0.f,0.f,0.f,0.f}};
  float sp[8] = {0,0,0,0,0,0,0,0};
  int nl = tid >> 3, dcol = (tid & 7)*8;
  const u16* kp0 = keb + (size_t)(b*NN + seg*256)*512 + h*64 + dcol;
  const u16* vp0 = vb  + (size_t)(b*NN + seg*256)*512 + h*64 + dcol;
  for (int nc = 0; nc < 256; nc += 32) {
    u16x8 ku = *(const u16x8*)(kp0 + (size_t)(nc + nl)*512);
    u16x8 vu = *(const u16x8*)(vp0 + (size_t)(nc + nl)*512);
    float a[8], bb[8];
    #pragma unroll
    for (int t = 0; t < 8; t++) { a[t] = bf2f(ku[t]); bb[t] = bf2f(vu[t]); sp[t] += a[t]; }
    *(float4*)&Ks[nl][dcol]   = (float4){a[0],a[1],a[2],a[3]};
    *(float4*)&Ks[nl][dcol+4] = (float4){a[4],a[5],a[6],a[7]};
    *(float4*)&Vs[nl][dcol]   = (float4){bb[0],bb[1],bb[2],bb[3]};
    *(float4*)&Vs[nl][dcol+4] = (float4){bb[4],bb[5],bb[6],bb[7]};
    __syncthreads();
    #pragma unroll
    for (int q = 0; q < 32; q++) {
      float4 a4 = *(const float4*)&Ks[q][ty*4];
      float4 b4 = *(const float4*)&Vs[q][tx*4];
      FMA16(a4, b4, acc)
    }
    __syncthreads();
  }
  #pragma unroll
  for (int j = 0; j < 8; j++) atomicAdd(&sS[dcol + j], sp[j]);
  float* cp = ctx + (size_t)bh*4096;
  #pragma unroll
  for (int i = 0; i < 4; i++)
    #pragma unroll
    for (int j = 0; j < 4; j++)
      atomicAdd(&cp[(ty*4 + i)*64 + tx*4 + j], acc[i][j]);
  __syncthreads();
  if (tid < 64) atomicAdd(&Sg[bh*64 + tid], sS[tid]);
}

// merged: ctxw (blocks 0..31) + cpad-edge-zero (blocks 32..351)
// W2t[b][o][h*64+d] = sum_e (ctx[b,h][d][e]/S[d]) * woutt[o][h*64+e]
__global__ __launch_bounds__(256) void ctxw_k(const float* ctx, const float* Sg, const u16* woutt,
                                              u16* W2t, u16* cpadb){
  int bx = blockIdx.x;
  int tid = threadIdx.x;
  if (bx >= 32) {
    int idx = (bx - 32)*256 + tid;
    if (idx < BB*40*512) {
      int c = idx & 511;
      int t = (idx >> 9) % 40;
      int b = idx / (40*512);
      int tt = (t < 20) ? t : 2048 + t;
      cpadb[((size_t)b*2088 + tt)*512 + c] = 0;
    }
    return;
  }
  int h = bx & 7, b = bx >> 3;
  int lane = tid & 63, wave = tid >> 6;
  int quad = lane >> 4, l16 = lane & 15;
  const float* cp = ctx + (size_t)(b*8 + h)*4096;
  fx4 acc[8][4] = {};
  #pragma unroll
  for (int ks = 0; ks < 2; ks++) {
    bf16x8 bfv[4];
    #pragma unroll
    for (int j = 0; j < 4; j++) {
      int d = j*16 + l16;
      float S = Sg[(b*8 + h)*64 + d];
      float rs = (S > 0.0f) ? 1.0f/S : 0.0f;
      const float* src = cp + d*64 + ks*32 + quad*8;
      float4 v0 = *(const float4*)src, v1 = *(const float4*)(src + 4);
      bf16x8 t;
      t[0]=(__bf16)(v0.x*rs); t[1]=(__bf16)(v0.y*rs); t[2]=(__bf16)(v0.z*rs); t[3]=(__bf16)(v0.w*rs);
      t[4]=(__bf16)(v1.x*rs); t[5]=(__bf16)(v1.y*rs); t[6]=(__bf16)(v1.z*rs); t[7]=(__bf16)(v1.w*rs);
      bfv[j] = t;
    }
    #pragma unroll
    for (int i = 0; i < 8; i++) {
      int orow = wave*128 + i*16 + l16;
      bf16x8 afr = __builtin_bit_cast(bf16x8, *(const u16x8*)&woutt[(size_t)orow*512 + h*64 + ks*32 + quad*8]);
      #pragma unroll
      for (int j = 0; j < 4; j++)
        acc[i][j] = __builtin_amdgcn_mfma_f32_16x16x32_bf16(afr, bfv[j], acc[i][j], 0, 0, 0);
    }
  }
  u16* out = W2t + (size_t)b*262144;
  #pragma unroll
  for (int i = 0; i < 8; i++)
    #pragma unroll
    for (int j = 0; j < 4; j++)
      #pragma unroll
      for (int r = 0; r < 4; r++) {
        int orow = wave*128 + i*16 + quad*4 + r;
        out[(size_t)orow*512 + h*64 + j*16 + l16] = f2bf(acc[i][j][r]);
      }
}

// ---- batched attn GEMM (M-tile 64): attnb = bf16(qb[b] @ W2t[b]^T + b_out); fused masked cpad ----
__global__ __launch_bounds__(256) void mgemm_attn64_k(const u16* qb, const u16* W2t, const float* bias,
                                                      const int* mask, u16* attnb, u16* cpadb){
  __shared__ u16 As[64][40];
  __shared__ u16 Bs[128][40];
  int tid = threadIdx.x;
  int lane = tid & 63;
  int wave = tid >> 6;
  int wn = wave * 32;
  int quad = lane >> 4, l16 = lane & 15;
  int m0 = blockIdx.y * 64, n0 = blockIdx.x * 128, b = blockIdx.z;
  const u16* A  = qb  + (size_t)b*2048*512;
  const u16* Bt = W2t + (size_t)b*262144;
  fx4 acc[4][2] = {};
  int ar = tid >> 2;
  int ac = (tid & 3) * 8;
  for (int k0 = 0; k0 < 512; k0 += 32) {
    *(u16x8*)&As[ar][ac]    = *(const u16x8*)&A[(size_t)(m0+ar)*512 + k0 + ac];
    *(u16x8*)&Bs[ar][ac]    = *(const u16x8*)&Bt[(size_t)(n0+ar)*512 + k0 + ac];
    *(u16x8*)&Bs[ar+64][ac] = *(const u16x8*)&Bt[(size_t)(n0+ar+64)*512 + k0 + ac];
    __syncthreads();
    bf16x8 af[4], bfv[2];
    #pragma unroll
    for (int i = 0; i < 4; i++)
      af[i] = __builtin_bit_cast(bf16x8, *(const u16x8*)&As[i*16 + l16][quad*8]);
    #pragma unroll
    for (int j = 0; j < 2; j++)
      bfv[j] = __builtin_bit_cast(bf16x8, *(const u16x8*)&Bs[wn + j*16 + l16][quad*8]);
    #pragma unroll
    for (int i = 0; i < 4; i++)
      #pragma unroll
      for (int j = 0; j < 2; j++)
        acc[i][j] = __builtin_amdgcn_mfma_f32_16x16x32_bf16(af[i], bfv[j], acc[i][j], 0, 0, 0);
    __syncthreads();
  }
  #pragma unroll
  for (int i = 0; i < 4; i++)
    #pragma unroll
    for (int j = 0; j < 2; j++) {
      int col = n0 + wn + j*16 + l16;
      float bv = bias[col];
      #pragma unroll
      for (int r = 0; r < 4; r++) {
        int row_l = m0 + i*16 + quad*4 + r;
        float v = acc[i][j][r] + bv;
        u16 vbb = f2bf(v);
        attnb[((size_t)b*2048 + row_l)*512 + col] = vbb;
        int mk = mask[b*2048 + row_l];
        cpadb[((size_t)b*2088 + row_l + 20)*512 + col] = mk ? vbb : (u16)0;
      }
    }
}

// ---- conv: 128t x 128o block, 2x2 waves of 64x64; A in LDS, WEIGHTS DIRECT FROM GLOBAL (L2) ----
// No Ws staging -> no inner barriers; weight loads pipeline across taps. LDS 24.2KB, grid 512 (2/CU).
__global__ __launch_bounds__(256, 2) void mconv7_k(const u16* cpad, const u16* Wn, const u16* Ww,
                                                   const float* bias_n, const float* bias_w,
                                                   u16* Dn, u16* Dw){
  __shared__ u16 As[168][72];
  int tid = threadIdx.x;
  int lane = tid & 63;
  int wave = tid >> 6;
  int wm = (wave >> 1) * 64;    // t-offset within 128
  int wo = (wave & 1) * 64;     // o-offset within 128
  int quad = lane >> 4, l16 = lane & 15;
  int o0 = blockIdx.x * 128, m0 = blockIdx.y * 128;
  int b = blockIdx.z >> 1, cid = blockIdx.z & 1;
  const u16* W = cid ? Ww : Wn;
  const float* bias = cid ? bias_w : bias_n;
  u16* D = cid ? Dw : Dn;
  fx4 acc[4][4] = {};
  const u16* cb = cpad + ((size_t)b*2088 + m0)*512;
  // per-lane weight base: rows o0+wo+l16 (+j*16), cols quad*8 (+ks*32) within [c0..c0+64)
  const u16* wlane = W + (size_t)(o0 + wo + l16)*512 + quad*8;
  for (int c0 = 0; c0 < 512; c0 += 64) {
    __syncthreads();   // previous chunk's readers of As done
    for (int idx = tid; idx < 168*8; idx += 256) {
      int r = idx >> 3, off = (idx & 7)*8;
      *(u16x8*)&As[r][off] = *(const u16x8*)&cb[(size_t)r*512 + c0 + off];
    }
    __syncthreads();
    #pragma unroll
    for (int kk = 0; kk < 9; kk++) {
      int shift = cid ? 5*kk : 16 + kk;
      const u16* wt = wlane + (size_t)kk*262144 + c0;
      #pragma unroll
      for (int ks = 0; ks < 2; ks++) {
        bf16x8 bfv[4];
        #pragma unroll
        for (int j = 0; j < 4; j++)
          bfv[j] = __builtin_bit_cast(bf16x8, *(const u16x8*)&wt[(size_t)j*8192 + ks*32]);
        #pragma unroll
        for (int i = 0; i < 4; i++) {
          bf16x8 afr = __builtin_bit_cast(bf16x8, *(const u16x8*)&As[shift + wm + i*16 + l16][ks*32 + quad*8]);
          #pragma unroll
          for (int j = 0; j < 4; j++)
            acc[i][j] = __builtin_amdgcn_mfma_f32_16x16x32_bf16(afr, bfv[j], acc[i][j], 0, 0, 0);
        }
      }
    }
  }
  #pragma unroll
  for (int i = 0; i < 4; i++)
    #pragma unroll
    for (int j = 0; j < 4; j++) {
      int col = o0 + wo + j*16 + l16;
      float bv = bias[col];
      #pragma unroll
      for (int r = 0; r < 4; r++) {
        int row = b*2048 + m0 + wm + i*16 + quad*4 + r;
        D[(size_t)row*512 + col] = f2bf(geluf(acc[i][j][r] + bv));
      }
    }
}

// ---------------- MFMA bf16 GEMM, M-tile 64, bf16 out ----------------
template<bool BIAS, bool GELU>
__global__ __launch_bounds__(256) void mgemm64b_k(const u16* A, const u16* Bt, const float* bias,
                                                  u16* C, int M, int N, int K){
  __shared__ u16 As[64][40];
  __shared__ u16 Bs[128][40];
  int tid = threadIdx.x;
  int lane = tid & 63;
  int wave = tid >> 6;
  int wn = wave * 32;
  int quad = lane >> 4, l16 = lane & 15;
  int m0 = blockIdx.y * 64, n0 = blockIdx.x * 128;
  fx4 acc[4][2] = {};
  int ar = tid >> 2;
  int ac = (tid & 3) * 8;
  for (int k0 = 0; k0 < K; k0 += 32) {
    *(u16x8*)&As[ar][ac]    = *(const u16x8*)&A[(size_t)(m0+ar)*K + k0 + ac];
    *(u16x8*)&Bs[ar][ac]    = *(const u16x8*)&Bt[(size_t)(n0+ar)*K + k0 + ac];
    *(u16x8*)&Bs[ar+64][ac] = *(const u16x8*)&Bt[(size_t)(n0+ar+64)*K + k0 + ac];
    __syncthreads();
    bf16x8 af[4], bfv[2];
    #pragma unroll
    for (int i = 0; i < 4; i++)
      af[i] = __builtin_bit_cast(bf16x8, *(const u16x8*)&As[i*16 + l16][quad*8]);
    #pragma unroll
    for (int j = 0; j < 2; j++)
      bfv[j] = __builtin_bit_cast(bf16x8, *(const u16x8*)&Bs[wn + j*16 + l16][quad*8]);
    #pragma unroll
    for (int i = 0; i < 4; i++)
      #pragma unroll
      for (int j = 0; j < 2; j++)
        acc[i][j] = __builtin_amdgcn_mfma_f32_16x16x32_bf16(af[i], bfv[j], acc[i][j], 0, 0, 0);
    __syncthreads();
  }
  #pragma unroll
  for (int i = 0; i < 4; i++)
    #pragma unroll
    for (int j = 0; j < 2; j++) {
      int col = n0 + wn + j*16 + l16;
      float bv = BIAS ? bias[col] : 0.0f;
      #pragma unroll
      for (int r = 0; r < 4; r++) {
        int row = m0 + i*16 + quad*4 + r;
        float v = acc[i][j][r] + bv;
        if (GELU) v = geluf(v);
        C[(size_t)row*N + col] = f2bf(v);
      }
    }
}

__device__ __forceinline__ float block_sum512(float v, float* red){
  #pragma unroll
  for (int o = 32; o; o >>= 1) v += __shfl_xor(v, o, 64);
  int w = threadIdx.x >> 6;
  if ((threadIdx.x & 63) == 0) red[w] = v;
  __syncthreads();
  float t = red[0] + red[1] + red[2] + red[3];
  __syncthreads();
  return t;
}

// LN over 512 with bf16 inputs; NADD extra inputs; OM=1: bf16 out; OM=2: flags[0]? fp32 : bf16
template<int NADD, int OM>
__global__ __launch_bounds__(256) void ln_k(const u16* X, const u16* Y, const u16* Z,
                                            const float* g, const float* be,
                                            const int* flags, void* out){
  __shared__ float red[4];
  size_t row = blockIdx.x;
  int tid = threadIdx.x;
  const u16* xp = X + row*512;
  float x0 = bf2f(xp[tid]), x1 = bf2f(xp[tid + 256]);
  if (NADD >= 1) { const u16* yp = Y + row*512; x0 += bf2f(yp[tid]); x1 += bf2f(yp[tid + 256]); }
  if (NADD >= 2) { const u16* zp = Z + row*512; x0 += bf2f(zp[tid]); x1 += bf2f(zp[tid + 256]); }
  float mean = block_sum512(x0 + x1, red) * (1.0f/512.0f);
  float d0 = x0 - mean, d1 = x1 - mean;
  float var = block_sum512(d0*d0 + d1*d1, red) * (1.0f/512.0f);
  float inv = rsqrtf(var + 1e-5f);
  float r0 = d0*inv*g[tid]       + be[tid];
  float r1 = d1*inv*g[tid + 256] + be[tid + 256];
  bool obf = (OM == 1) || (OM == 2 && !flags[0]);
  if (obf) {
    u16* op = (u16*)out;
    op[row*512 + tid]       = f2bf(r0);
    op[row*512 + tid + 256] = f2bf(r1);
  } else {
    float* op = (float*)out;
    op[row*512 + tid]       = r0;
    op[row*512 + tid + 256] = r1;
  }
}

extern "C" void kernel_launch(void* const* d_in, const int* in_sizes, int n_in,
                              void* d_out, int out_size, void* d_ws, size_t ws_size,
                              hipStream_t stream) {
  const void* tokens   = d_in[0];
  const void* mask     = d_in[1];
  const void* w_qkv    = d_in[2];
  const void* w_out    = d_in[3];
  const void* b_out    = d_in[4];
  const void* w_narrow = d_in[5];
  const void* b_narrow = d_in[6];
  const void* w_wide   = d_in[7];
  const void* b_wide   = d_in[8];
  const void* ln1_g    = d_in[9];
  const void* ln1_b    = d_in[10];
  const void* ff_w     = d_in[11];
  const void* ff_b     = d_in[12];
  const void* ln2_g    = d_in[13];
  const void* ln2_b    = d_in[14];

  float* ws = (float*)d_ws;
  int*   flags  = (int*)ws;                    // 16
  int*   m32    = (int*)(ws + 16);             // 8192 -> 8208
  float* params = ws + 8208;                   // 4096 -> 12304
  float* kS     = ws + 12304;                  // 2048 -> 14352
  float* ctx    = ws + 14352;                  // 131072 -> 145424
  float* rope   = ws + 145424;                 // 131072 -> 276496
  u16*   tokbf  = (u16*)(ws + 276496);         // 4194304 u16 -> 2373648
  u16*   wqkvt  = (u16*)(ws + 2373648);        // 786432 u16 -> 2766864
  u16*   woutt  = (u16*)(ws + 2766864);        // 262144 u16 -> 2897936
  u16*   ffwt   = (u16*)(ws + 2897936);        // 262144 u16 -> 3029008
  u16*   wtN2   = (u16*)(ws + 3029008);        // 2359296 u16 -> 4208656
  u16*   wtW2   = (u16*)(ws + 4208656);        // 2359296 u16 -> 5388304
  u16*   qb     = (u16*)(ws + 5388304);        // 4194304 u16 -> 7485456
  u16*   keb    = (u16*)(ws + 7485456);        // 4194304 u16 -> 9582608
  u16*   vb     = (u16*)(ws + 9582608);        // 4194304 u16 -> 11679760
  u16*   W2t    = (u16*)(ws + 11679760);       // 1048576 u16 -> 12204048
  u16*   attnb  = (u16*)(ws + 12204048);       // 4194304 u16 -> 14301200
  u16*   cpadb  = (u16*)(ws + 14301200);       // 4276224 u16 -> 16439312
  u16*   Dnb    = (u16*)(ws + 16439312);       // 4194304 u16 -> 18536464
  u16*   Dwb    = (u16*)(ws + 18536464);       // 4194304 u16 -> 20633616 (~82.5 MB)
  u16*   Eb     = attnb;                       // attnb dead after ln1
  u16*   t1b    = tokbf;                       // tokens dead after qkv gemm

  float* p_bout = params;        float* p_bnar = params + 512;
  float* p_bwid = params + 1024; float* p_l1g  = params + 1536;
  float* p_l1b  = params + 2048; float* p_ffb  = params + 2560;
  float* p_l2g  = params + 3072; float* p_l2b  = params + 3584;

  sniff_k<<<dim3(1), dim3(256), 0, stream>>>((const u16*)tokens, (const unsigned int*)mask, flags);
  misc_k<<<dim3(8192), dim3(256), 0, stream>>>(mask, tokens, b_out, b_narrow, b_wide, ln1_g, ln1_b,
                                               ff_b, ln2_g, ln2_b, flags, rope, m32, params, ctx,
                                               kS, tokbf);
  prep2_k<<<dim3(1600), dim3(256), 0, stream>>>(w_qkv, w_out, ff_w, w_narrow, w_wide, flags,
                                                wqkvt, woutt, ffwt, wtN2, wtW2);

  // qkv GEMM with fused q-softmax / k-exp / v-mask epilogue (M=0 softmax trick)
  mgemm_qkv_k<<<dim3(12, 64), dim3(256), 0, stream>>>(
      tokbf, wqkvt, rope, m32, qb, keb, vb);

  // ctx = ke^T @ v (+ S accumulation), bf16 inputs
  ctx_k<<<dim3(32, 8), dim3(256), 0, stream>>>(keb, vb, ctx, kS);

  // W2t[b] = (blockdiag(ctx_b)/S) @ w_out; + cpad edge zero
  ctxw_k<<<dim3(352), dim3(256), 0, stream>>>(ctx, kS, woutt, W2t, cpadb);

  // attn = qb @ W2t[b]^T + b_out (bf16); fused masked cpad write
  mgemm_attn64_k<<<dim3(4, 32, 4), dim3(256), 0, stream>>>(qb, W2t, p_bout, m32, attnb, cpadb);

  // convs: weights direct from global (L2), A in LDS, no inner barriers
  mconv7_k<<<dim3(4, 16, 8), dim3(256), 0, stream>>>(cpadb, wtN2, wtW2, p_bnar, p_bwid, Dnb, Dwb);

  // t1 = LN(attn + Dn + Dw) -> bf16
  ln_k<2,1><<<dim3(NROWS), dim3(256), 0, stream>>>(attnb, Dnb, Dwb, p_l1g, p_l1b, flags, (void*)t1b);

  // E = gelu(t1 @ ff_w + ff_b) -> bf16
  mgemm64b_k<true,true><<<dim3(4, 128), dim3(256), 0, stream>>>(
      t1b, ffwt, p_ffb, Eb, NROWS, 512, 512);

  // out = LN(E) -> d_out, dtype per flags
  ln_k<0,2><<<dim3(NROWS), dim3(256), 0, stream>>>(Eb, nullptr, nullptr, p_l2g, p_l2b, flags, d_out);
}